// Round 9
// baseline (212.746 us; speedup 1.0000x reference)
//
#include <hip/hip_runtime.h>
#include <hip/hip_bf16.h>

#define NN 10000
#define NE 320000

typedef __bf16 bf16x8 __attribute__((ext_vector_type(8)));
typedef float  f32x4  __attribute__((ext_vector_type(4)));

__device__ __forceinline__ float bf2f(ushort u){
  union { uint i; float f; } c; c.i = ((uint)u) << 16; return c.f;
}
__device__ __forceinline__ ushort f2bf(float f){
  union { float f; uint i; } c; c.f = f;
  uint x = c.i;
  return (ushort)((x + 0x7FFFu + ((x >> 16) & 1u)) >> 16);
}
__device__ __forceinline__ float gelu_erf(float x){
  return 0.5f * x * (1.0f + erff(x * 0.70710678118654752f));
}
__device__ __forceinline__ uint encf(float f){
  uint u = __float_as_uint(f);
  return (u & 0x80000000u) ? ~u : (u | 0x80000000u);
}
__device__ __forceinline__ float decf(uint u){
  return __uint_as_float((u & 0x80000000u) ? (u & 0x7FFFFFFFu) : ~u);
}
#define MFMA16(a,b,c) __builtin_amdgcn_mfma_f32_16x16x32_bf16((a),(b),(c),0,0,0)

// ---------------- init: flag (block 0) + cnt/last/Menc/S init (blocks 1..79) ----------------
__global__ void k_init(const uint* __restrict__ w, int* __restrict__ flag,
                       int* __restrict__ cnt, int* __restrict__ last,
                       uint* __restrict__ Menc, float* __restrict__ S){
  int t = threadIdx.x;
  if (blockIdx.x == 0){
    uint c = 0;
    for (int i = t; i < 4096; i += 256){
      uint v = w[i * 63];
      uint e = (v >> 7) & 0xFF;
      if (e >= 100 && e <= 140) c++;
    }
    __shared__ uint red[256];
    red[t] = c; __syncthreads();
    for (int s = 128; s > 0; s >>= 1){
      if (t < s) red[t] += red[t + s];
      __syncthreads();
    }
    if (t == 0) *flag = (red[0] < 2048) ? 1 : 0;
    return;
  }
  int idx = (blockIdx.x - 1) * 256 + t;
  if (idx < 10000) last[idx] = -1;
  else if (idx < 20000) cnt[idx - 10000] = 0;
  else if (idx < 20008) Menc[idx - 20000] = 0u;
  else if (idx < 20016) S[idx - 20008] = 0.f;
}

// ---------------- prep: count + cvt + zeros + weight transposes ----------------
__global__ void k_prep(
    const void* NF0, const int* __restrict__ dstI,
    const void* w1, const void* w2, const void* qw, const void* kvw,
    const void* ow1, const void* ow2,
    const void* b1, const void* b2, const void* qb, const void* kvb,
    const void* ob1, const void* ob2, const void* lg, const void* lb,
    int* __restrict__ cnt, int* __restrict__ last,
    ushort* NFc, float* Gagg, ushort* SB, ushort* KVW2,
    ushort* W1aT, ushort* W1bT, ushort* W1cT, ushort* W2T, ushort* QT, ushort* KVT,
    ushort* O1aT, ushort* O1bT, ushort* O2T, const int* flag)
{
  int f = *flag;
  int idx = blockIdx.x * 256 + threadIdx.x;
  if (idx < NE){
    int d = dstI[idx];
    atomicAdd(&cnt[d], 1);
    atomicMax(&last[d], idx);
    return;
  }
  idx -= NE;
  if (idx < 320000){
    if (f){
      float4 v = ((const float4*)NF0)[idx];
      ushort4 o; o.x=f2bf(v.x); o.y=f2bf(v.y); o.z=f2bf(v.z); o.w=f2bf(v.w);
      ((ushort4*)NFc)[idx] = o;
    } else ((ushort4*)NFc)[idx] = ((const ushort4*)NF0)[idx];
    return;
  }
  idx -= 320000;
  if (idx < 320000){ float4 z = {0.f,0.f,0.f,0.f}; ((float4*)Gagg)[idx] = z; return; }
  idx -= 320000;
  if (idx < 1024){
    const void* ps[8] = {b1,b2,qb,kvb,ob1,ob2,lg,lb};
    const void* p = ps[idx >> 7]; int j = idx & 127;
    SB[idx] = f ? f2bf(((const float*)p)[j]) : ((const ushort*)p)[j];
    return;
  }
  idx -= 1024;
  if (idx < 8192){
    KVW2[idx] = f ? f2bf(((const float*)kvw)[16384 + idx]) : ((const ushort*)kvw)[16384 + idx];
    return;
  }
  idx -= 8192;
  if (idx < 16384){ int c=idx>>7,k=idx&127; W1aT[idx] = f? f2bf(((const float*)w1)[k*128+c]) : ((const ushort*)w1)[k*128+c]; return; }
  idx -= 16384;
  if (idx < 16384){ int c=idx>>7,k=idx&127; W1bT[idx] = f? f2bf(((const float*)w1)[(128+k)*128+c]) : ((const ushort*)w1)[(128+k)*128+c]; return; }
  idx -= 16384;
  if (idx < 8192){ int c=idx>>6,k=idx&63;  W1cT[idx] = f? f2bf(((const float*)w1)[(256+k)*128+c]) : ((const ushort*)w1)[(256+k)*128+c]; return; }
  idx -= 8192;
  if (idx < 16384){ int c=idx>>7,k=idx&127; W2T[idx] = f? f2bf(((const float*)w2)[k*128+c]) : ((const ushort*)w2)[k*128+c]; return; }
  idx -= 16384;
  if (idx < 16384){ int c=idx>>7,k=idx&127; QT[idx]  = f? f2bf(((const float*)qw)[k*128+c]) : ((const ushort*)qw)[k*128+c]; return; }
  idx -= 16384;
  if (idx < 16384){ int c=idx>>7,k=idx&127; KVT[idx] = f? f2bf(((const float*)kvw)[k*128+c]) : ((const ushort*)kvw)[k*128+c]; return; }
  idx -= 16384;
  if (idx < 16384){ int c=idx>>7,k=idx&127; O1aT[idx] = f? f2bf(((const float*)ow1)[k*128+c]) : ((const ushort*)ow1)[k*128+c]; return; }
  idx -= 16384;
  if (idx < 16384){ int c=idx>>7,k=idx&127; O1bT[idx] = f? f2bf(((const float*)ow1)[(128+k)*128+c]) : ((const ushort*)ow1)[(128+k)*128+c]; return; }
  idx -= 16384;
  if (idx < 16384){ int c=idx>>7,k=idx&127; O2T[idx] = f? f2bf(((const float*)ow2)[k*128+c]) : ((const ushort*)ow2)[k*128+c]; return; }
}

// ---------------- scan ----------------
__global__ __launch_bounds__(1024) void k_scan(const int* __restrict__ cnt,
                                               int* __restrict__ fill){
  __shared__ int sc[1024];
  int t = threadIdx.x;
  int base = t * 10;
  int v[10]; int tot = 0;
  #pragma unroll
  for (int j = 0; j < 10; ++j){
    int idx = base + j;
    v[j] = (idx < NN) ? cnt[idx] : 0;
    tot += v[j];
  }
  sc[t] = tot; __syncthreads();
  for (int off = 1; off < 1024; off <<= 1){
    int x = (t >= off) ? sc[t - off] : 0;
    __syncthreads();
    sc[t] += x;
    __syncthreads();
  }
  int run = sc[t] - tot;
  #pragma unroll
  for (int j = 0; j < 10; ++j){
    int idx = base + j;
    if (idx < NN) fill[idx] = run;
    run += v[j];
  }
}

// ---------------- fill + EA permute/convert (blocks 0..1249) + nodepack (1250..1874) ----------------
__global__ __launch_bounds__(256) void k_fillperm(
    const int* __restrict__ srcI, const int* __restrict__ dstI,
    int* __restrict__ fill, int* __restrict__ sSort, int* __restrict__ dSort,
    const float* __restrict__ EAf, const ushort* __restrict__ EAb,
    ushort* __restrict__ EAs,
    const ushort* __restrict__ NFc,
    const ushort* __restrict__ W1aT, const ushort* __restrict__ W1bT,
    const ushort* __restrict__ QT,  const ushort* __restrict__ KVT,
    const ushort* __restrict__ SB,
    ushort* __restrict__ PA, ushort* __restrict__ PB,
    ushort* __restrict__ Qb, ushort* __restrict__ KV1,
    const int* __restrict__ flag)
{
  int t = threadIdx.x;
  if (blockIdx.x >= 1250){
    // ---- nodepack: PA, PB(+b1), Qb(+qb), KV1(+kvb) ----
    int l = t & 63, w = t >> 6;
    int m = l & 15, g = l >> 4;
    int row0 = ((int)blockIdx.x - 1250) * 16;
    const ushort* WT = (w==0) ? W1aT : (w==1) ? W1bT : (w==2) ? QT : KVT;
    ushort*       OUT= (w==0) ? PA   : (w==1) ? PB   : (w==2) ? Qb : KV1;
    const f32x4 FZ = {0.f,0.f,0.f,0.f};
    f32x4 acc[8];
    #pragma unroll
    for (int i = 0; i < 8; ++i) acc[i] = FZ;
    int arow = row0 + m;
    #pragma unroll
    for (int ks = 0; ks < 4; ++ks){
      int koff = ks * 32 + g * 8;
      bf16x8 a = *reinterpret_cast<const bf16x8*>(NFc + (size_t)arow * 128 + koff);
      #pragma unroll
      for (int nt = 0; nt < 8; ++nt){
        bf16x8 b = *reinterpret_cast<const bf16x8*>(WT + (size_t)(nt*16+m) * 128 + koff);
        acc[nt] = MFMA16(a, b, acc[nt]);
      }
    }
    #pragma unroll
    for (int nt = 0; nt < 8; ++nt){
      int col = nt * 16 + m;
      float bb = (w==1) ? bf2f(SB[col]) : (w==2) ? bf2f(SB[256+col]) : (w==3) ? bf2f(SB[384+col]) : 0.f;
      #pragma unroll
      for (int r = 0; r < 4; ++r){
        int row = row0 + g * 4 + r;
        OUT[(size_t)row * 128 + col] = f2bf(acc[nt][r] + bb);
      }
    }
    return;
  }
  // ---- fill + permute ----
  __shared__ int sp[256];
  int e0 = blockIdx.x * 256;
  int e = e0 + t;
  {
    int d = dstI[e];
    int p = atomicAdd(&fill[d], 1);
    sSort[p] = srcI[e];
    dSort[p] = d;
    sp[t] = p;
  }
  __syncthreads();
  if (*flag){
    #pragma unroll
    for (int pass = 0; pass < 16; ++pass){
      int i = pass * 256 + t;
      int rloc = i >> 4, q = i & 15;
      int p = sp[rloc];
      float4 v = *reinterpret_cast<const float4*>(EAf + (size_t)(e0 + rloc) * 64 + q * 4);
      ushort4 o; o.x=f2bf(v.x); o.y=f2bf(v.y); o.z=f2bf(v.z); o.w=f2bf(v.w);
      *reinterpret_cast<ushort4*>(EAs + (size_t)p * 64 + q * 4) = o;
    }
  } else {
    #pragma unroll
    for (int pass = 0; pass < 8; ++pass){
      int i = pass * 256 + t;
      int rloc = i >> 3, q = i & 7;
      int p = sp[rloc];
      *reinterpret_cast<bf16x8*>(EAs + (size_t)p * 64 + q * 8) =
        *reinterpret_cast<const bf16x8*>(EAb + (size_t)(e0 + rloc) * 64 + q * 8);
    }
  }
}

// ---------------- edge (blocks 0..4999, 64 edges each) + attn (5000..5624) ----------------
__global__ __launch_bounds__(256) void k_edgeattn(
    const ushort* __restrict__ PA, const ushort* __restrict__ PB,
    const ushort* __restrict__ EAs,
    const int* __restrict__ sSort, const int* __restrict__ dSort,
    const ushort* __restrict__ W1cT,
    float* __restrict__ Gagg,
    const ushort* __restrict__ Qb, const ushort* __restrict__ KV1,
    const ushort* __restrict__ EAb, const float* __restrict__ EAf,
    const ushort* __restrict__ KVW2,
    const int* __restrict__ srcI, const int* __restrict__ last,
    float* __restrict__ attn, uint* __restrict__ Menc, const int* __restrict__ flag)
{
  __shared__ __align__(16) char Hs[64 * 256];   // 16KB; attn branch overlays ea_s here
  __shared__ float LUT[1026];
  __shared__ int sIdx[64], dIdx[64];
  __shared__ int eN[16], sN[16];
  __shared__ uint lmax[8];
  int t = threadIdx.x;

  if (blockIdx.x >= 5000){
    // ---------- attention logits ----------
    float (*ea_s)[64] = reinterpret_cast<float(*)[64]>(Hs);
    int n0 = ((int)blockIdx.x - 5000) * 16;
    if (t < 16){
      int e = last[n0 + t];
      eN[t] = e;
      sN[t] = (e >= 0) ? srcI[e] : 0;
    }
    if (t < 8) lmax[t] = 0u;
    __syncthreads();
    int F = *flag;
    for (int i = t; i < 1024; i += 256){
      int nn = i >> 6, k = i & 63;
      int e = eN[nn];
      int ee = (e >= 0) ? e : 0;
      float v = F ? EAf[(size_t)ee * 64 + k] : bf2f(EAb[(size_t)ee * 64 + k]);
      ea_s[nn][k] = (e >= 0) ? v : 0.0f;
    }
    __syncthreads();
    int j = t & 127;
    int half = t >> 7;
    float acc[8];
    #pragma unroll
    for (int i = 0; i < 8; ++i) acc[i] = 0.f;
    for (int k = 0; k < 64; ++k){
      float wv = bf2f(KVW2[(size_t)k * 128 + j]);
      #pragma unroll
      for (int nn = 0; nn < 8; ++nn) acc[nn] += ea_s[half * 8 + nn][k] * wv;
    }
    #pragma unroll
    for (int nn = 0; nn < 8; ++nn){
      int nl = half * 8 + nn;
      int n = n0 + nl;
      int e = eN[nl];
      float kvv = acc[nn] + bf2f(KV1[(size_t)sN[nl] * 128 + j]);
      float qv  = bf2f(Qb[(size_t)n * 128 + j]);
      float p = qv * kvv;
      p += __shfl_xor(p, 1); p += __shfl_xor(p, 2);
      p += __shfl_xor(p, 4); p += __shfl_xor(p, 8);
      if ((j & 15) == 0 && e >= 0){
        float v = p * 0.25f;
        attn[(size_t)n * 8 + (j >> 4)] = v;
        atomicMax(&lmax[j >> 4], encf(v));
      }
    }
    __syncthreads();
    if (t < 8 && lmax[t]) atomicMax(&Menc[t], lmax[t]);
    return;
  }

  // ---------- edge MLP + segmented reduce (64-edge tile) ----------
  int p0 = blockIdx.x * 64;
  int l = t & 63, w = t >> 6;
  int m = l & 15, g = l >> 4;

  if (t < 64){ sIdx[t] = sSort[p0 + t]; dIdx[t] = dSort[p0 + t]; }
  // gelu LUT over [-8, 8], 1/64 step
  for (int i = t; i < 1025; i += 256) LUT[i] = gelu_erf((float)i * (1.0f/64.0f) - 8.0f);
  __syncthreads();

  // stage PS = PA[src]+PB[dst] into Hs (swizzled): 4 threads/row, 4 octets each
  {
    int r = t >> 2, q = t & 3;
    int sr = sIdx[r], dr = dIdx[r];
    #pragma unroll
    for (int j = 0; j < 4; ++j){
      int c8 = q * 4 + j;
      bf16x8 pa = *reinterpret_cast<const bf16x8*>(PA + (size_t)sr * 128 + c8 * 8);
      bf16x8 pb = *reinterpret_cast<const bf16x8*>(PB + (size_t)dr * 128 + c8 * 8);
      bf16x8 ps;
      #pragma unroll
      for (int k = 0; k < 8; ++k) ps[k] = (__bf16)((float)pa[k] + (float)pb[k]);
      int byte = (r * 256 + c8 * 16) ^ ((r & 7) << 4);
      *reinterpret_cast<bf16x8*>(&Hs[byte]) = ps;
    }
  }

  // EA GEMM: each wave owns 16 rows x 128 cols, K=64
  const f32x4 FZ = {0.f,0.f,0.f,0.f};
  f32x4 acc[8];
  #pragma unroll
  for (int i = 0; i < 8; ++i) acc[i] = FZ;

  #pragma unroll
  for (int ks = 0; ks < 2; ++ks){
    bf16x8 af = *reinterpret_cast<const bf16x8*>(EAs + (size_t)(p0 + w * 16 + m) * 64 + ks * 32 + g * 8);
    #pragma unroll
    for (int nt = 0; nt < 8; ++nt){
      bf16x8 b = *reinterpret_cast<const bf16x8*>(W1cT + (size_t)(nt * 16 + m) * 64 + ks * 32 + g * 8);
      acc[nt] = MFMA16(af, b, acc[nt]);
    }
  }
  __syncthreads();   // PS staged & LUT built

  // G = gelu(acc + PS) via LUT; write back to same LDS slot (same-thread RMW, safe)
  #pragma unroll
  for (int nt = 0; nt < 8; ++nt){
    int col = nt * 16 + m;
    #pragma unroll
    for (int r = 0; r < 4; ++r){
      int row = w * 16 + g * 4 + r;
      int byte = (row * 256 + col * 2) ^ ((row & 7) << 4);
      float x = acc[nt][r] + bf2f(*reinterpret_cast<const ushort*>(&Hs[byte]));
      float idxf = fminf(fmaxf((x + 8.0f) * 64.0f, 0.0f), 1023.0f);
      int i = (int)idxf;
      float fr = idxf - (float)i;
      float y = LUT[i] + fr * (LUT[i + 1] - LUT[i]);
      y = (x > 7.9f) ? x : y;
      y = (x < -7.9f) ? 0.0f : y;
      *reinterpret_cast<ushort*>(&Hs[byte]) = f2bf(y);
    }
  }
  __syncthreads();

  // column-per-thread segmented reduce: wave-uniform flush, contiguous lanes per atomic
  {
    int c = t & 127, hh = t >> 7;
    int rS = hh * 32, rE = rS + 32;
    float run = 0.f;
    int cur = dIdx[rS];
    for (int r = rS; r < rE; ++r){
      int d = dIdx[r];
      if (d != cur){
        unsafeAtomicAdd(&Gagg[(size_t)cur * 128 + c], run);
        run = 0.f; cur = d;
      }
      int byte = (r * 256 + c * 2) ^ ((r & 7) << 4);
      run += bf2f(*reinterpret_cast<const ushort*>(&Hs[byte]));
    }
    unsafeAtomicAdd(&Gagg[(size_t)cur * 128 + c], run);
  }
}

// ---------------- softmax denominators ----------------
__global__ __launch_bounds__(256) void k_asum(
    const float* __restrict__ attn, const int* __restrict__ last,
    const uint* __restrict__ Menc, float* __restrict__ S)
{
  __shared__ float red[256][8];
  int t = threadIdx.x;
  float M[8];
  #pragma unroll
  for (int h = 0; h < 8; ++h) M[h] = decf(Menc[h]);
  float p[8];
  #pragma unroll
  for (int h = 0; h < 8; ++h) p[h] = 0.f;
  for (int n = blockIdx.x * 256 + t; n < NN; n += gridDim.x * 256){
    if (last[n] >= 0){
      #pragma unroll
      for (int h = 0; h < 8; ++h) p[h] += __expf(attn[(size_t)n * 8 + h] - M[h]);
    }
  }
  #pragma unroll
  for (int h = 0; h < 8; ++h) red[t][h] = p[h];
  __syncthreads();
  for (int s = 128; s > 0; s >>= 1){
    if (t < s){
      #pragma unroll
      for (int h = 0; h < 8; ++h) red[t][h] += red[t + s][h];
    }
    __syncthreads();
  }
  if (t < 8) atomicAdd(&S[t], red[0][t]);
}

// ---------------- fused: (Gagg@W2 + cnt·b2)·aw -> LDS -> @O1b + NF@O1a + ob1 -> gelu -> T1 ----------------
__global__ __launch_bounds__(256) void k_aggmm2(
    const float* __restrict__ Gagg, const ushort* __restrict__ W2T,
    const ushort* __restrict__ O1aT, const ushort* __restrict__ O1bT,
    const ushort* __restrict__ SB,           // b2=SB+128, ob1=SB+512
    const int* __restrict__ cnt, const int* __restrict__ last,
    const float* __restrict__ attn, const uint* __restrict__ Menc,
    const float* __restrict__ S,
    const ushort* __restrict__ NFc, ushort* __restrict__ T1)
{
  __shared__ __align__(16) char Zs[64 * 256];
  int t = threadIdx.x, l = t & 63, w = t >> 6;
  int m = l & 15, g = l >> 4;
  int row0 = blockIdx.x * 64 + w * 16;

  float M[8], Sinv[8];
  #pragma unroll
  for (int h = 0; h < 8; ++h){ M[h] = decf(Menc[h]); Sinv[h] = 1.0f / S[h]; }

  int arow = row0 + m; if (arow >= NN) arow = NN - 1;
  const f32x4 FZ = {0.f,0.f,0.f,0.f};
  f32x4 acc[8];
  #pragma unroll
  for (int i = 0; i < 8; ++i) acc[i] = FZ;

  #pragma unroll
  for (int ks = 0; ks < 4; ++ks){
    const float* gp = Gagg + (size_t)arow * 128 + ks * 32 + g * 8;
    float4 u0 = *reinterpret_cast<const float4*>(gp);
    float4 u1 = *reinterpret_cast<const float4*>(gp + 4);
    float gv[8] = {u0.x,u0.y,u0.z,u0.w,u1.x,u1.y,u1.z,u1.w};
    bf16x8 hi, lo;
    #pragma unroll
    for (int k = 0; k < 8; ++k){
      hi[k] = (__bf16)gv[k];
      lo[k] = (__bf16)(gv[k] - (float)hi[k]);
    }
    #pragma unroll
    for (int nt = 0; nt < 8; ++nt){
      bf16x8 b = *reinterpret_cast<const bf16x8*>(W2T + (size_t)(nt*16+m) * 128 + ks * 32 + g * 8);
      acc[nt] = MFMA16(hi, b, acc[nt]);
      acc[nt] = MFMA16(lo, b, acc[nt]);
    }
  }

  #pragma unroll
  for (int r = 0; r < 4; ++r){
    int row = row0 + g * 4 + r;
    int rr = (row < NN) ? row : NN - 1;
    float cn = (float)cnt[rr];
    int lst = last[rr];
    int Lr = w * 16 + g * 4 + r;
    #pragma unroll
    for (int nt = 0; nt < 8; ++nt){
      int col = nt * 16 + m;
      float aw = (lst >= 0) ? __expf(attn[(size_t)rr * 8 + nt] - M[nt]) * Sinv[nt] : 0.f;
      float z = (acc[nt][r] + cn * bf2f(SB[128 + col])) * aw;
      int byte = (Lr * 256 + col * 2) ^ ((Lr & 7) << 4);
      *reinterpret_cast<ushort*>(&Zs[byte]) = f2bf(z);
    }
  }
  __syncthreads();

  f32x4 acc2[8];
  #pragma unroll
  for (int i = 0; i < 8; ++i) acc2[i] = FZ;
  int La = w * 16 + m;
  #pragma unroll
  for (int ks = 0; ks < 4; ++ks){
    int koff = ks * 32 + g * 8;
    bf16x8 az = *reinterpret_cast<const bf16x8*>(&Zs[(La * 256 + koff * 2) ^ ((La & 7) << 4)]);
    bf16x8 an = *reinterpret_cast<const bf16x8*>(NFc + (size_t)arow * 128 + koff);
    #pragma unroll
    for (int nt = 0; nt < 8; ++nt){
      bf16x8 b1v = *reinterpret_cast<const bf16x8*>(O1bT + (size_t)(nt*16+m) * 128 + koff);
      bf16x8 b2v = *reinterpret_cast<const bf16x8*>(O1aT + (size_t)(nt*16+m) * 128 + koff);
      acc2[nt] = MFMA16(az, b1v, acc2[nt]);
      acc2[nt] = MFMA16(an, b2v, acc2[nt]);
    }
  }
  #pragma unroll
  for (int nt = 0; nt < 8; ++nt){
    int col = nt * 16 + m;
    float bb = bf2f(SB[512 + col]);
    #pragma unroll
    for (int r = 0; r < 4; ++r){
      int row = row0 + g * 4 + r;
      if (row < NN){
        float v = gelu_erf(acc2[nt][r] + bb);
        T1[(size_t)row * 128 + col] = f2bf(v);
      }
    }
  }
}

// ---------------- final GEMM + residual + LayerNorm ----------------
__global__ __launch_bounds__(256) void k_out2ln(
    const ushort* __restrict__ T1, const ushort* __restrict__ O2T,
    const ushort* __restrict__ SB,    // ob2=SB+640, ln_g=SB+768, ln_b=SB+896
    const ushort* __restrict__ NFc, void* __restrict__ out,
    const int* __restrict__ flag)
{
  int t = threadIdx.x, l = t & 63, w = t >> 6;
  int m = l & 15, g = l >> 4;
  int row0 = blockIdx.x * 64 + w * 16;
  int F = *flag;
  int arow = row0 + m; if (arow >= NN) arow = NN - 1;
  const f32x4 FZ = {0.f,0.f,0.f,0.f};
  f32x4 acc[8];
  #pragma unroll
  for (int i = 0; i < 8; ++i) acc[i] = FZ;
  #pragma unroll
  for (int ks = 0; ks < 4; ++ks){
    int koff = ks * 32 + g * 8;
    bf16x8 a = *reinterpret_cast<const bf16x8*>(T1 + (size_t)arow * 128 + koff);
    #pragma unroll
    for (int nt = 0; nt < 8; ++nt){
      bf16x8 b = *reinterpret_cast<const bf16x8*>(O2T + (size_t)(nt*16+m) * 128 + koff);
      acc[nt] = MFMA16(a, b, acc[nt]);
    }
  }
  #pragma unroll
  for (int r = 0; r < 4; ++r){
    int row = row0 + g * 4 + r;
    bool ok = row < NN;
    int rr = ok ? row : NN - 1;
    float x[8]; float s = 0.f, q = 0.f;
    #pragma unroll
    for (int nt = 0; nt < 8; ++nt){
      int col = nt * 16 + m;
      float xv = acc[nt][r] + bf2f(SB[640 + col]) + bf2f(NFc[(size_t)rr * 128 + col]);
      x[nt] = xv; s += xv; q += xv * xv;
    }
    #pragma unroll
    for (int msk = 1; msk < 16; msk <<= 1){
      s += __shfl_xor(s, msk);
      q += __shfl_xor(q, msk);
    }
    float mean = s * (1.0f / 128.0f);
    float var  = q * (1.0f / 128.0f) - mean * mean;
    float rs = rsqrtf(var + 1e-5f);
    if (ok){
      #pragma unroll
      for (int nt = 0; nt < 8; ++nt){
        int col = nt * 16 + m;
        float y = (x[nt] - mean) * rs * bf2f(SB[768 + col]) + bf2f(SB[896 + col]);
        if (F) ((float*)out)[(size_t)row * 128 + col] = y;
        else   ((ushort*)out)[(size_t)row * 128 + col] = f2bf(y);
      }
    }
  }
}

// ---------------- host ----------------
extern "C" void kernel_launch(void* const* d_in, const int* in_sizes, int n_in,
                              void* d_out, int out_size, void* d_ws, size_t ws_size,
                              hipStream_t stream)
{
  const void* NF0  = d_in[0];
  const void* EA0  = d_in[1];
  const void* w1   = d_in[2];
  const void* b1   = d_in[3];
  const void* w2   = d_in[4];
  const void* b2   = d_in[5];
  const void* qw   = d_in[6];
  const void* qb   = d_in[7];
  const void* kvw  = d_in[8];
  const void* kvb  = d_in[9];
  const void* ow1  = d_in[10];
  const void* ob1  = d_in[11];
  const void* ow2  = d_in[12];
  const void* ob2  = d_in[13];
  const void* lg   = d_in[14];
  const void* lb   = d_in[15];
  const int*  srcI = (const int*)d_in[16];
  const int*  dstI = srcI + NE;

  char* ws = (char*)d_ws;
  size_t off = 0;
  auto alloc = [&](size_t bytes) -> void* {
    void* p = ws + off;
    off = (off + bytes + 255) & ~(size_t)255;
    return p;
  };
  int*    flag  = (int*)   alloc(4);
  ushort* NFc   = (ushort*)alloc((size_t)NN * 128 * 2);
  ushort* SB    = (ushort*)alloc(8 * 128 * 2);
  ushort* KVW2  = (ushort*)alloc(64 * 128 * 2);
  ushort* W1aT  = (ushort*)alloc(128 * 128 * 2);
  ushort* W1bT  = (ushort*)alloc(128 * 128 * 2);
  ushort* W1cT  = (ushort*)alloc(128 * 64 * 2);
  ushort* W2T   = (ushort*)alloc(128 * 128 * 2);
  ushort* QT    = (ushort*)alloc(128 * 128 * 2);
  ushort* KVT   = (ushort*)alloc(128 * 128 * 2);
  ushort* O1aT  = (ushort*)alloc(128 * 128 * 2);
  ushort* O1bT  = (ushort*)alloc(128 * 128 * 2);
  ushort* O2T   = (ushort*)alloc(128 * 128 * 2);
  int*    last  = (int*)   alloc(NN * 4);
  int*    cnt   = (int*)   alloc(NN * 4);
  int*    fill  = (int*)   alloc(NN * 4);
  int*    sSort = (int*)   alloc((size_t)NE * 4);
  int*    dSort = (int*)   alloc((size_t)NE * 4);
  ushort* EAs   = (ushort*)alloc((size_t)NE * 64 * 2);
  float*  attn  = (float*) alloc(NN * 8 * 4);
  uint*   Menc  = (uint*)  alloc(8 * 4);
  float*  S     = (float*) alloc(8 * 4);
  ushort* PA    = (ushort*)alloc((size_t)NN * 128 * 2);
  ushort* PB    = (ushort*)alloc((size_t)NN * 128 * 2);
  ushort* Qb    = (ushort*)alloc((size_t)NN * 128 * 2);
  ushort* KV1   = (ushort*)alloc((size_t)NN * 128 * 2);
  float*  Gagg  = (float*) alloc((size_t)NN * 128 * 4);
  ushort* T1    = (ushort*)alloc((size_t)NN * 128 * 2);

  k_init<<<80, 256, 0, stream>>>((const uint*)NF0, flag, cnt, last, Menc, S);
  k_prep<<<4330, 256, 0, stream>>>(NF0, dstI, w1, w2, qw, kvw, ow1, ow2,
                                   b1, b2, qb, kvb, ob1, ob2, lg, lb,
                                   cnt, last, NFc, Gagg, SB, KVW2,
                                   W1aT, W1bT, W1cT, W2T, QT, KVT, O1aT, O1bT, O2T, flag);
  k_scan<<<1, 1024, 0, stream>>>(cnt, fill);
  k_fillperm<<<1875, 256, 0, stream>>>(srcI, dstI, fill, sSort, dSort,
                                       (const float*)EA0, (const ushort*)EA0, EAs,
                                       NFc, W1aT, W1bT, QT, KVT, SB,
                                       PA, PB, Qb, KV1, flag);
  k_edgeattn<<<5625, 256, 0, stream>>>(PA, PB, EAs, sSort, dSort, W1cT, Gagg,
                                       Qb, KV1, (const ushort*)EA0, (const float*)EA0,
                                       KVW2, srcI, last, attn, Menc, flag);
  k_asum<<<40, 256, 0, stream>>>(attn, last, Menc, S);
  k_aggmm2<<<157, 256, 0, stream>>>(Gagg, W2T, O1aT, O1bT, SB, cnt, last,
                                    attn, Menc, S, NFc, T1);
  k_out2ln<<<157, 256, 0, stream>>>(T1, O2T, SB, NFc, d_out, flag);
}

// Round 10
// 201.985 us; speedup vs baseline: 1.0533x; 1.0533x over previous
//
#include <hip/hip_runtime.h>
#include <hip/hip_bf16.h>

#define NN 10000
#define NE 320000

typedef __bf16 bf16x8 __attribute__((ext_vector_type(8)));
typedef float  f32x4  __attribute__((ext_vector_type(4)));

__device__ __forceinline__ float bf2f(ushort u){
  union { uint i; float f; } c; c.i = ((uint)u) << 16; return c.f;
}
__device__ __forceinline__ ushort f2bf(float f){
  union { float f; uint i; } c; c.f = f;
  uint x = c.i;
  return (ushort)((x + 0x7FFFu + ((x >> 16) & 1u)) >> 16);
}
__device__ __forceinline__ float gelu_erf(float x){
  return 0.5f * x * (1.0f + erff(x * 0.70710678118654752f));
}
__device__ __forceinline__ float gelu_tanh(float x){
  float y = 0.7978845608028654f * (x + 0.044715f * x * x * x);
  float e = __expf(2.f * y);
  float th = 1.f - 2.f / (e + 1.f);
  return 0.5f * x * (1.f + th);
}
__device__ __forceinline__ uint encf(float f){
  uint u = __float_as_uint(f);
  return (u & 0x80000000u) ? ~u : (u | 0x80000000u);
}
__device__ __forceinline__ float decf(uint u){
  return __uint_as_float((u & 0x80000000u) ? (u & 0x7FFFFFFFu) : ~u);
}
#define MFMA16(a,b,c) __builtin_amdgcn_mfma_f32_16x16x32_bf16((a),(b),(c),0,0,0)

// ---------------- init: flag (block 0) + cnt/last/Menc/S init (blocks 1..79) ----------------
__global__ void k_init(const uint* __restrict__ w, int* __restrict__ flag,
                       int* __restrict__ cnt, int* __restrict__ last,
                       uint* __restrict__ Menc, float* __restrict__ S){
  int t = threadIdx.x;
  if (blockIdx.x == 0){
    uint c = 0;
    for (int i = t; i < 4096; i += 256){
      uint v = w[i * 63];
      uint e = (v >> 7) & 0xFF;
      if (e >= 100 && e <= 140) c++;
    }
    __shared__ uint red[256];
    red[t] = c; __syncthreads();
    for (int s = 128; s > 0; s >>= 1){
      if (t < s) red[t] += red[t + s];
      __syncthreads();
    }
    if (t == 0) *flag = (red[0] < 2048) ? 1 : 0;
    return;
  }
  int idx = (blockIdx.x - 1) * 256 + t;
  if (idx < 10000) last[idx] = -1;
  else if (idx < 20000) cnt[idx - 10000] = 0;
  else if (idx < 20008) Menc[idx - 20000] = 0u;
  else if (idx < 20016) S[idx - 20008] = 0.f;
}

// ---------------- prep: count + cvt + zeros + weight transposes ----------------
__global__ void k_prep(
    const void* NF0, const int* __restrict__ dstI,
    const void* w1, const void* w2, const void* qw, const void* kvw,
    const void* ow1, const void* ow2,
    const void* b1, const void* b2, const void* qb, const void* kvb,
    const void* ob1, const void* ob2, const void* lg, const void* lb,
    int* __restrict__ cnt, int* __restrict__ last,
    ushort* NFc, float* Gagg, ushort* SB, ushort* KVW2,
    ushort* W1aT, ushort* W1bT, ushort* W1cT, ushort* W2T, ushort* QT, ushort* KVT,
    ushort* O1aT, ushort* O1bT, ushort* O2T, const int* flag)
{
  int f = *flag;
  int idx = blockIdx.x * 256 + threadIdx.x;
  if (idx < NE){
    int d = dstI[idx];
    atomicAdd(&cnt[d], 1);
    atomicMax(&last[d], idx);
    return;
  }
  idx -= NE;
  if (idx < 320000){
    if (f){
      float4 v = ((const float4*)NF0)[idx];
      ushort4 o; o.x=f2bf(v.x); o.y=f2bf(v.y); o.z=f2bf(v.z); o.w=f2bf(v.w);
      ((ushort4*)NFc)[idx] = o;
    } else ((ushort4*)NFc)[idx] = ((const ushort4*)NF0)[idx];
    return;
  }
  idx -= 320000;
  if (idx < 320000){ float4 z = {0.f,0.f,0.f,0.f}; ((float4*)Gagg)[idx] = z; return; }
  idx -= 320000;
  if (idx < 1024){
    const void* ps[8] = {b1,b2,qb,kvb,ob1,ob2,lg,lb};
    const void* p = ps[idx >> 7]; int j = idx & 127;
    SB[idx] = f ? f2bf(((const float*)p)[j]) : ((const ushort*)p)[j];
    return;
  }
  idx -= 1024;
  if (idx < 8192){
    KVW2[idx] = f ? f2bf(((const float*)kvw)[16384 + idx]) : ((const ushort*)kvw)[16384 + idx];
    return;
  }
  idx -= 8192;
  if (idx < 16384){ int c=idx>>7,k=idx&127; W1aT[idx] = f? f2bf(((const float*)w1)[k*128+c]) : ((const ushort*)w1)[k*128+c]; return; }
  idx -= 16384;
  if (idx < 16384){ int c=idx>>7,k=idx&127; W1bT[idx] = f? f2bf(((const float*)w1)[(128+k)*128+c]) : ((const ushort*)w1)[(128+k)*128+c]; return; }
  idx -= 16384;
  if (idx < 8192){ int c=idx>>6,k=idx&63;  W1cT[idx] = f? f2bf(((const float*)w1)[(256+k)*128+c]) : ((const ushort*)w1)[(256+k)*128+c]; return; }
  idx -= 8192;
  if (idx < 16384){ int c=idx>>7,k=idx&127; W2T[idx] = f? f2bf(((const float*)w2)[k*128+c]) : ((const ushort*)w2)[k*128+c]; return; }
  idx -= 16384;
  if (idx < 16384){ int c=idx>>7,k=idx&127; QT[idx]  = f? f2bf(((const float*)qw)[k*128+c]) : ((const ushort*)qw)[k*128+c]; return; }
  idx -= 16384;
  if (idx < 16384){ int c=idx>>7,k=idx&127; KVT[idx] = f? f2bf(((const float*)kvw)[k*128+c]) : ((const ushort*)kvw)[k*128+c]; return; }
  idx -= 16384;
  if (idx < 16384){ int c=idx>>7,k=idx&127; O1aT[idx] = f? f2bf(((const float*)ow1)[k*128+c]) : ((const ushort*)ow1)[k*128+c]; return; }
  idx -= 16384;
  if (idx < 16384){ int c=idx>>7,k=idx&127; O1bT[idx] = f? f2bf(((const float*)ow1)[(128+k)*128+c]) : ((const ushort*)ow1)[(128+k)*128+c]; return; }
  idx -= 16384;
  if (idx < 16384){ int c=idx>>7,k=idx&127; O2T[idx] = f? f2bf(((const float*)ow2)[k*128+c]) : ((const ushort*)ow2)[k*128+c]; return; }
}

// ---------------- scan ----------------
__global__ __launch_bounds__(1024) void k_scan(const int* __restrict__ cnt,
                                               int* __restrict__ fill){
  __shared__ int sc[1024];
  int t = threadIdx.x;
  int base = t * 10;
  int v[10]; int tot = 0;
  #pragma unroll
  for (int j = 0; j < 10; ++j){
    int idx = base + j;
    v[j] = (idx < NN) ? cnt[idx] : 0;
    tot += v[j];
  }
  sc[t] = tot; __syncthreads();
  for (int off = 1; off < 1024; off <<= 1){
    int x = (t >= off) ? sc[t - off] : 0;
    __syncthreads();
    sc[t] += x;
    __syncthreads();
  }
  int run = sc[t] - tot;
  #pragma unroll
  for (int j = 0; j < 10; ++j){
    int idx = base + j;
    if (idx < NN) fill[idx] = run;
    run += v[j];
  }
}

// ---------------- fill (blocks 0..1249) + nodepack (1250..1874) ----------------
__global__ __launch_bounds__(256) void k_fillperm(
    const int* __restrict__ srcI, const int* __restrict__ dstI,
    int* __restrict__ fill, int* __restrict__ sSort, int* __restrict__ dSort,
    int* __restrict__ eSort,
    const ushort* __restrict__ NFc,
    const ushort* __restrict__ W1aT, const ushort* __restrict__ W1bT,
    const ushort* __restrict__ QT,  const ushort* __restrict__ KVT,
    const ushort* __restrict__ SB,
    ushort* __restrict__ PA, ushort* __restrict__ PB,
    ushort* __restrict__ Qb, ushort* __restrict__ KV1)
{
  int t = threadIdx.x;
  if (blockIdx.x >= 1250){
    // ---- nodepack: PA, PB(+b1), Qb(+qb), KV1(+kvb) ----
    int l = t & 63, w = t >> 6;
    int m = l & 15, g = l >> 4;
    int row0 = ((int)blockIdx.x - 1250) * 16;
    const ushort* WT = (w==0) ? W1aT : (w==1) ? W1bT : (w==2) ? QT : KVT;
    ushort*       OUT= (w==0) ? PA   : (w==1) ? PB   : (w==2) ? Qb : KV1;
    const f32x4 FZ = {0.f,0.f,0.f,0.f};
    f32x4 acc[8];
    #pragma unroll
    for (int i = 0; i < 8; ++i) acc[i] = FZ;
    int arow = row0 + m;
    #pragma unroll
    for (int ks = 0; ks < 4; ++ks){
      int koff = ks * 32 + g * 8;
      bf16x8 a = *reinterpret_cast<const bf16x8*>(NFc + (size_t)arow * 128 + koff);
      #pragma unroll
      for (int nt = 0; nt < 8; ++nt){
        bf16x8 b = *reinterpret_cast<const bf16x8*>(WT + (size_t)(nt*16+m) * 128 + koff);
        acc[nt] = MFMA16(a, b, acc[nt]);
      }
    }
    #pragma unroll
    for (int nt = 0; nt < 8; ++nt){
      int col = nt * 16 + m;
      float bb = (w==1) ? bf2f(SB[col]) : (w==2) ? bf2f(SB[256+col]) : (w==3) ? bf2f(SB[384+col]) : 0.f;
      #pragma unroll
      for (int r = 0; r < 4; ++r){
        int row = row0 + g * 4 + r;
        OUT[(size_t)row * 128 + col] = f2bf(acc[nt][r] + bb);
      }
    }
    return;
  }
  // ---- fill: sorted index arrays only (EA gathered later in k_edgeattn) ----
  int e = blockIdx.x * 256 + t;
  int d = dstI[e];
  int p = atomicAdd(&fill[d], 1);
  sSort[p] = srcI[e];
  dSort[p] = d;
  eSort[p] = e;
}

// ---------------- edge (blocks 0..4999, 64 edges, gathered EA) + attn (5000..5624) ----------------
__global__ __launch_bounds__(256) void k_edgeattn(
    const ushort* __restrict__ PA, const ushort* __restrict__ PB,
    const int* __restrict__ sSort, const int* __restrict__ dSort,
    const int* __restrict__ eSort,
    const ushort* __restrict__ W1cT,
    float* __restrict__ Gagg,
    const ushort* __restrict__ Qb, const ushort* __restrict__ KV1,
    const ushort* __restrict__ EAb, const float* __restrict__ EAf,
    const ushort* __restrict__ KVW2,
    const int* __restrict__ srcI, const int* __restrict__ last,
    float* __restrict__ attn, uint* __restrict__ Menc, const int* __restrict__ flag)
{
  __shared__ __align__(16) char Hs[64 * 256];    // 16KB; attn branch overlays ea_s here
  __shared__ __align__(16) char EAl[64 * 128];   // 8KB gathered EA tile (bf16, swizzled)
  __shared__ int sIdx[64], dIdx[64], eIdx[64];
  __shared__ int eN[16], sN[16];
  __shared__ uint lmax[8];
  int t = threadIdx.x;

  if (blockIdx.x >= 5000){
    // ---------- attention logits ----------
    float (*ea_s)[64] = reinterpret_cast<float(*)[64]>(Hs);
    int n0 = ((int)blockIdx.x - 5000) * 16;
    if (t < 16){
      int e = last[n0 + t];
      eN[t] = e;
      sN[t] = (e >= 0) ? srcI[e] : 0;
    }
    if (t < 8) lmax[t] = 0u;
    __syncthreads();
    int F = *flag;
    for (int i = t; i < 1024; i += 256){
      int nn = i >> 6, k = i & 63;
      int e = eN[nn];
      int ee = (e >= 0) ? e : 0;
      float v = F ? EAf[(size_t)ee * 64 + k] : bf2f(EAb[(size_t)ee * 64 + k]);
      ea_s[nn][k] = (e >= 0) ? v : 0.0f;
    }
    __syncthreads();
    int j = t & 127;
    int half = t >> 7;
    float acc[8];
    #pragma unroll
    for (int i = 0; i < 8; ++i) acc[i] = 0.f;
    for (int k = 0; k < 64; ++k){
      float wv = bf2f(KVW2[(size_t)k * 128 + j]);
      #pragma unroll
      for (int nn = 0; nn < 8; ++nn) acc[nn] += ea_s[half * 8 + nn][k] * wv;
    }
    #pragma unroll
    for (int nn = 0; nn < 8; ++nn){
      int nl = half * 8 + nn;
      int n = n0 + nl;
      int e = eN[nl];
      float kvv = acc[nn] + bf2f(KV1[(size_t)sN[nl] * 128 + j]);
      float qv  = bf2f(Qb[(size_t)n * 128 + j]);
      float p = qv * kvv;
      p += __shfl_xor(p, 1); p += __shfl_xor(p, 2);
      p += __shfl_xor(p, 4); p += __shfl_xor(p, 8);
      if ((j & 15) == 0 && e >= 0){
        float v = p * 0.25f;
        attn[(size_t)n * 8 + (j >> 4)] = v;
        atomicMax(&lmax[j >> 4], encf(v));
      }
    }
    __syncthreads();
    if (t < 8 && lmax[t]) atomicMax(&Menc[t], lmax[t]);
    return;
  }

  // ---------- edge MLP + segmented reduce (64-edge tile) ----------
  int p0 = blockIdx.x * 64;
  int l = t & 63, w = t >> 6;
  int m = l & 15, g = l >> 4;

  if (t < 64){ sIdx[t] = sSort[p0 + t]; dIdx[t] = dSort[p0 + t]; eIdx[t] = eSort[p0 + t]; }
  __syncthreads();
  int F = *flag;

  // stage gathered EA row -> EAl (bf16, swizzled) and PS = PA[src]+PB[dst] -> Hs
  {
    int r = t >> 2, q = t & 3;          // 4 threads per row
    int e = eIdx[r];
    int kb = q * 32;                     // byte offset within 128B bf16 row
    if (F){
      const float* src = EAf + (size_t)e * 64 + q * 16;
      float4 v0 = *reinterpret_cast<const float4*>(src);
      float4 v1 = *reinterpret_cast<const float4*>(src + 4);
      float4 v2 = *reinterpret_cast<const float4*>(src + 8);
      float4 v3 = *reinterpret_cast<const float4*>(src + 12);
      bf16x8 o0, o1;
      o0[0]=(__bf16)v0.x; o0[1]=(__bf16)v0.y; o0[2]=(__bf16)v0.z; o0[3]=(__bf16)v0.w;
      o0[4]=(__bf16)v1.x; o0[5]=(__bf16)v1.y; o0[6]=(__bf16)v1.z; o0[7]=(__bf16)v1.w;
      o1[0]=(__bf16)v2.x; o1[1]=(__bf16)v2.y; o1[2]=(__bf16)v2.z; o1[3]=(__bf16)v2.w;
      o1[4]=(__bf16)v3.x; o1[5]=(__bf16)v3.y; o1[6]=(__bf16)v3.z; o1[7]=(__bf16)v3.w;
      *reinterpret_cast<bf16x8*>(&EAl[(r * 128 + kb)      ^ ((r & 7) << 4)]) = o0;
      *reinterpret_cast<bf16x8*>(&EAl[(r * 128 + kb + 16) ^ ((r & 7) << 4)]) = o1;
    } else {
      const ushort* src = EAb + (size_t)e * 64 + q * 16;
      *reinterpret_cast<bf16x8*>(&EAl[(r * 128 + kb)      ^ ((r & 7) << 4)]) =
        *reinterpret_cast<const bf16x8*>(src);
      *reinterpret_cast<bf16x8*>(&EAl[(r * 128 + kb + 16) ^ ((r & 7) << 4)]) =
        *reinterpret_cast<const bf16x8*>(src + 8);
    }
    int sr = sIdx[r], dr = dIdx[r];
    #pragma unroll
    for (int j = 0; j < 4; ++j){
      int c8 = q * 4 + j;
      bf16x8 pa = *reinterpret_cast<const bf16x8*>(PA + (size_t)sr * 128 + c8 * 8);
      bf16x8 pb = *reinterpret_cast<const bf16x8*>(PB + (size_t)dr * 128 + c8 * 8);
      bf16x8 ps;
      #pragma unroll
      for (int k = 0; k < 8; ++k) ps[k] = (__bf16)((float)pa[k] + (float)pb[k]);
      int byte = (r * 256 + c8 * 16) ^ ((r & 7) << 4);
      *reinterpret_cast<bf16x8*>(&Hs[byte]) = ps;
    }
  }
  __syncthreads();

  // EA GEMM: each wave owns 16 rows x 128 cols, K=64; A from LDS (2-way conflict = free)
  const f32x4 FZ = {0.f,0.f,0.f,0.f};
  f32x4 acc[8];
  #pragma unroll
  for (int i = 0; i < 8; ++i) acc[i] = FZ;

  #pragma unroll
  for (int ks = 0; ks < 2; ++ks){
    int row = w * 16 + m;
    bf16x8 af = *reinterpret_cast<const bf16x8*>(&EAl[(row * 128 + ks * 64 + g * 16) ^ ((row & 7) << 4)]);
    #pragma unroll
    for (int nt = 0; nt < 8; ++nt){
      bf16x8 b = *reinterpret_cast<const bf16x8*>(W1cT + (size_t)(nt * 16 + m) * 64 + ks * 32 + g * 8);
      acc[nt] = MFMA16(af, b, acc[nt]);
    }
  }

  // G = gelu(acc + PS); write back to same LDS slot (same-thread RMW, safe)
  #pragma unroll
  for (int nt = 0; nt < 8; ++nt){
    int col = nt * 16 + m;
    #pragma unroll
    for (int r = 0; r < 4; ++r){
      int row = w * 16 + g * 4 + r;
      int byte = (row * 256 + col * 2) ^ ((row & 7) << 4);
      float x = acc[nt][r] + bf2f(*reinterpret_cast<const ushort*>(&Hs[byte]));
      *reinterpret_cast<ushort*>(&Hs[byte]) = f2bf(gelu_tanh(x));
    }
  }
  __syncthreads();

  // column-per-thread segmented reduce: wave-uniform flush, contiguous lanes per atomic
  {
    int c = t & 127, hh = t >> 7;
    int rS = hh * 32, rE = rS + 32;
    float run = 0.f;
    int cur = dIdx[rS];
    for (int r = rS; r < rE; ++r){
      int d = dIdx[r];
      if (d != cur){
        unsafeAtomicAdd(&Gagg[(size_t)cur * 128 + c], run);
        run = 0.f; cur = d;
      }
      int byte = (r * 256 + c * 2) ^ ((r & 7) << 4);
      run += bf2f(*reinterpret_cast<const ushort*>(&Hs[byte]));
    }
    unsafeAtomicAdd(&Gagg[(size_t)cur * 128 + c], run);
  }
}

// ---------------- softmax denominators ----------------
__global__ __launch_bounds__(256) void k_asum(
    const float* __restrict__ attn, const int* __restrict__ last,
    const uint* __restrict__ Menc, float* __restrict__ S)
{
  __shared__ float red[256][8];
  int t = threadIdx.x;
  float M[8];
  #pragma unroll
  for (int h = 0; h < 8; ++h) M[h] = decf(Menc[h]);
  float p[8];
  #pragma unroll
  for (int h = 0; h < 8; ++h) p[h] = 0.f;
  for (int n = blockIdx.x * 256 + t; n < NN; n += gridDim.x * 256){
    if (last[n] >= 0){
      #pragma unroll
      for (int h = 0; h < 8; ++h) p[h] += __expf(attn[(size_t)n * 8 + h] - M[h]);
    }
  }
  #pragma unroll
  for (int h = 0; h < 8; ++h) red[t][h] = p[h];
  __syncthreads();
  for (int s = 128; s > 0; s >>= 1){
    if (t < s){
      #pragma unroll
      for (int h = 0; h < 8; ++h) red[t][h] += red[t + s][h];
    }
    __syncthreads();
  }
  if (t < 8) atomicAdd(&S[t], red[0][t]);
}

// ---------------- fused: (Gagg@W2 + cnt·b2)·aw -> LDS -> @O1b + NF@O1a + ob1 -> gelu -> T1 ----------------
__global__ __launch_bounds__(256) void k_aggmm2(
    const float* __restrict__ Gagg, const ushort* __restrict__ W2T,
    const ushort* __restrict__ O1aT, const ushort* __restrict__ O1bT,
    const ushort* __restrict__ SB,           // b2=SB+128, ob1=SB+512
    const int* __restrict__ cnt, const int* __restrict__ last,
    const float* __restrict__ attn, const uint* __restrict__ Menc,
    const float* __restrict__ S,
    const ushort* __restrict__ NFc, ushort* __restrict__ T1)
{
  __shared__ __align__(16) char Zs[64 * 256];
  int t = threadIdx.x, l = t & 63, w = t >> 6;
  int m = l & 15, g = l >> 4;
  int row0 = blockIdx.x * 64 + w * 16;

  float M[8], Sinv[8];
  #pragma unroll
  for (int h = 0; h < 8; ++h){ M[h] = decf(Menc[h]); Sinv[h] = 1.0f / S[h]; }

  int arow = row0 + m; if (arow >= NN) arow = NN - 1;
  const f32x4 FZ = {0.f,0.f,0.f,0.f};
  f32x4 acc[8];
  #pragma unroll
  for (int i = 0; i < 8; ++i) acc[i] = FZ;

  #pragma unroll
  for (int ks = 0; ks < 4; ++ks){
    const float* gp = Gagg + (size_t)arow * 128 + ks * 32 + g * 8;
    float4 u0 = *reinterpret_cast<const float4*>(gp);
    float4 u1 = *reinterpret_cast<const float4*>(gp + 4);
    float gv[8] = {u0.x,u0.y,u0.z,u0.w,u1.x,u1.y,u1.z,u1.w};
    bf16x8 hi, lo;
    #pragma unroll
    for (int k = 0; k < 8; ++k){
      hi[k] = (__bf16)gv[k];
      lo[k] = (__bf16)(gv[k] - (float)hi[k]);
    }
    #pragma unroll
    for (int nt = 0; nt < 8; ++nt){
      bf16x8 b = *reinterpret_cast<const bf16x8*>(W2T + (size_t)(nt*16+m) * 128 + ks * 32 + g * 8);
      acc[nt] = MFMA16(hi, b, acc[nt]);
      acc[nt] = MFMA16(lo, b, acc[nt]);
    }
  }

  #pragma unroll
  for (int r = 0; r < 4; ++r){
    int row = row0 + g * 4 + r;
    int rr = (row < NN) ? row : NN - 1;
    float cn = (float)cnt[rr];
    int lst = last[rr];
    int Lr = w * 16 + g * 4 + r;
    #pragma unroll
    for (int nt = 0; nt < 8; ++nt){
      int col = nt * 16 + m;
      float aw = (lst >= 0) ? __expf(attn[(size_t)rr * 8 + nt] - M[nt]) * Sinv[nt] : 0.f;
      float z = (acc[nt][r] + cn * bf2f(SB[128 + col])) * aw;
      int byte = (Lr * 256 + col * 2) ^ ((Lr & 7) << 4);
      *reinterpret_cast<ushort*>(&Zs[byte]) = f2bf(z);
    }
  }
  __syncthreads();

  f32x4 acc2[8];
  #pragma unroll
  for (int i = 0; i < 8; ++i) acc2[i] = FZ;
  int La = w * 16 + m;
  #pragma unroll
  for (int ks = 0; ks < 4; ++ks){
    int koff = ks * 32 + g * 8;
    bf16x8 az = *reinterpret_cast<const bf16x8*>(&Zs[(La * 256 + koff * 2) ^ ((La & 7) << 4)]);
    bf16x8 an = *reinterpret_cast<const bf16x8*>(NFc + (size_t)arow * 128 + koff);
    #pragma unroll
    for (int nt = 0; nt < 8; ++nt){
      bf16x8 b1v = *reinterpret_cast<const bf16x8*>(O1bT + (size_t)(nt*16+m) * 128 + koff);
      bf16x8 b2v = *reinterpret_cast<const bf16x8*>(O1aT + (size_t)(nt*16+m) * 128 + koff);
      acc2[nt] = MFMA16(az, b1v, acc2[nt]);
      acc2[nt] = MFMA16(an, b2v, acc2[nt]);
    }
  }
  #pragma unroll
  for (int nt = 0; nt < 8; ++nt){
    int col = nt * 16 + m;
    float bb = bf2f(SB[512 + col]);
    #pragma unroll
    for (int r = 0; r < 4; ++r){
      int row = row0 + g * 4 + r;
      if (row < NN){
        float v = gelu_erf(acc2[nt][r] + bb);
        T1[(size_t)row * 128 + col] = f2bf(v);
      }
    }
  }
}

// ---------------- final GEMM + residual + LayerNorm ----------------
__global__ __launch_bounds__(256) void k_out2ln(
    const ushort* __restrict__ T1, const ushort* __restrict__ O2T,
    const ushort* __restrict__ SB,    // ob2=SB+640, ln_g=SB+768, ln_b=SB+896
    const ushort* __restrict__ NFc, void* __restrict__ out,
    const int* __restrict__ flag)
{
  int t = threadIdx.x, l = t & 63, w = t >> 6;
  int m = l & 15, g = l >> 4;
  int row0 = blockIdx.x * 64 + w * 16;
  int F = *flag;
  int arow = row0 + m; if (arow >= NN) arow = NN - 1;
  const f32x4 FZ = {0.f,0.f,0.f,0.f};
  f32x4 acc[8];
  #pragma unroll
  for (int i = 0; i < 8; ++i) acc[i] = FZ;
  #pragma unroll
  for (int ks = 0; ks < 4; ++ks){
    int koff = ks * 32 + g * 8;
    bf16x8 a = *reinterpret_cast<const bf16x8*>(T1 + (size_t)arow * 128 + koff);
    #pragma unroll
    for (int nt = 0; nt < 8; ++nt){
      bf16x8 b = *reinterpret_cast<const bf16x8*>(O2T + (size_t)(nt*16+m) * 128 + koff);
      acc[nt] = MFMA16(a, b, acc[nt]);
    }
  }
  #pragma unroll
  for (int r = 0; r < 4; ++r){
    int row = row0 + g * 4 + r;
    bool ok = row < NN;
    int rr = ok ? row : NN - 1;
    float x[8]; float s = 0.f, q = 0.f;
    #pragma unroll
    for (int nt = 0; nt < 8; ++nt){
      int col = nt * 16 + m;
      float xv = acc[nt][r] + bf2f(SB[640 + col]) + bf2f(NFc[(size_t)rr * 128 + col]);
      x[nt] = xv; s += xv; q += xv * xv;
    }
    #pragma unroll
    for (int msk = 1; msk < 16; msk <<= 1){
      s += __shfl_xor(s, msk);
      q += __shfl_xor(q, msk);
    }
    float mean = s * (1.0f / 128.0f);
    float var  = q * (1.0f / 128.0f) - mean * mean;
    float rs = rsqrtf(var + 1e-5f);
    if (ok){
      #pragma unroll
      for (int nt = 0; nt < 8; ++nt){
        int col = nt * 16 + m;
        float y = (x[nt] - mean) * rs * bf2f(SB[768 + col]) + bf2f(SB[896 + col]);
        if (F) ((float*)out)[(size_t)row * 128 + col] = y;
        else   ((ushort*)out)[(size_t)row * 128 + col] = f2bf(y);
      }
    }
  }
}

// ---------------- host ----------------
extern "C" void kernel_launch(void* const* d_in, const int* in_sizes, int n_in,
                              void* d_out, int out_size, void* d_ws, size_t ws_size,
                              hipStream_t stream)
{
  const void* NF0  = d_in[0];
  const void* EA0  = d_in[1];
  const void* w1   = d_in[2];
  const void* b1   = d_in[3];
  const void* w2   = d_in[4];
  const void* b2   = d_in[5];
  const void* qw   = d_in[6];
  const void* qb   = d_in[7];
  const void* kvw  = d_in[8];
  const void* kvb  = d_in[9];
  const void* ow1  = d_in[10];
  const void* ob1  = d_in[11];
  const void* ow2  = d_in[12];
  const void* ob2  = d_in[13];
  const void* lg   = d_in[14];
  const void* lb   = d_in[15];
  const int*  srcI = (const int*)d_in[16];
  const int*  dstI = srcI + NE;

  char* ws = (char*)d_ws;
  size_t off = 0;
  auto alloc = [&](size_t bytes) -> void* {
    void* p = ws + off;
    off = (off + bytes + 255) & ~(size_t)255;
    return p;
  };
  int*    flag  = (int*)   alloc(4);
  ushort* NFc   = (ushort*)alloc((size_t)NN * 128 * 2);
  ushort* SB    = (ushort*)alloc(8 * 128 * 2);
  ushort* KVW2  = (ushort*)alloc(64 * 128 * 2);
  ushort* W1aT  = (ushort*)alloc(128 * 128 * 2);
  ushort* W1bT  = (ushort*)alloc(128 * 128 * 2);
  ushort* W1cT  = (ushort*)alloc(128 * 64 * 2);
  ushort* W2T   = (ushort*)alloc(128 * 128 * 2);
  ushort* QT    = (ushort*)alloc(128 * 128 * 2);
  ushort* KVT   = (ushort*)alloc(128 * 128 * 2);
  ushort* O1aT  = (ushort*)alloc(128 * 128 * 2);
  ushort* O1bT  = (ushort*)alloc(128 * 128 * 2);
  ushort* O2T   = (ushort*)alloc(128 * 128 * 2);
  int*    last  = (int*)   alloc(NN * 4);
  int*    cnt   = (int*)   alloc(NN * 4);
  int*    fill  = (int*)   alloc(NN * 4);
  int*    sSort = (int*)   alloc((size_t)NE * 4);
  int*    dSort = (int*)   alloc((size_t)NE * 4);
  int*    eSort = (int*)   alloc((size_t)NE * 4);
  float*  attn  = (float*) alloc(NN * 8 * 4);
  uint*   Menc  = (uint*)  alloc(8 * 4);
  float*  S     = (float*) alloc(8 * 4);
  ushort* PA    = (ushort*)alloc((size_t)NN * 128 * 2);
  ushort* PB    = (ushort*)alloc((size_t)NN * 128 * 2);
  ushort* Qb    = (ushort*)alloc((size_t)NN * 128 * 2);
  ushort* KV1   = (ushort*)alloc((size_t)NN * 128 * 2);
  float*  Gagg  = (float*) alloc((size_t)NN * 128 * 4);
  ushort* T1    = (ushort*)alloc((size_t)NN * 128 * 2);

  k_init<<<80, 256, 0, stream>>>((const uint*)NF0, flag, cnt, last, Menc, S);
  k_prep<<<4330, 256, 0, stream>>>(NF0, dstI, w1, w2, qw, kvw, ow1, ow2,
                                   b1, b2, qb, kvb, ob1, ob2, lg, lb,
                                   cnt, last, NFc, Gagg, SB, KVW2,
                                   W1aT, W1bT, W1cT, W2T, QT, KVT, O1aT, O1bT, O2T, flag);
  k_scan<<<1, 1024, 0, stream>>>(cnt, fill);
  k_fillperm<<<1875, 256, 0, stream>>>(srcI, dstI, fill, sSort, dSort, eSort,
                                       NFc, W1aT, W1bT, QT, KVT, SB,
                                       PA, PB, Qb, KV1);
  k_edgeattn<<<5625, 256, 0, stream>>>(PA, PB, sSort, dSort, eSort, W1cT, Gagg,
                                       Qb, KV1, (const ushort*)EA0, (const float*)EA0,
                                       KVW2, srcI, last, attn, Menc, flag);
  k_asum<<<40, 256, 0, stream>>>(attn, last, Menc, S);
  k_aggmm2<<<157, 256, 0, stream>>>(Gagg, W2T, O1aT, O1bT, SB, cnt, last,
                                    attn, Menc, S, NFc, T1);
  k_out2ln<<<157, 256, 0, stream>>>(T1, O2T, SB, NFc, d_out, flag);
}

// Round 11
// 197.814 us; speedup vs baseline: 1.0755x; 1.0211x over previous
//
#include <hip/hip_runtime.h>
#include <hip/hip_bf16.h>

#define NN 10000
#define NE 320000

typedef __bf16 bf16x8 __attribute__((ext_vector_type(8)));
typedef float  f32x4  __attribute__((ext_vector_type(4)));

__device__ __forceinline__ float bf2f(ushort u){
  union { uint i; float f; } c; c.i = ((uint)u) << 16; return c.f;
}
__device__ __forceinline__ ushort f2bf(float f){
  union { float f; uint i; } c; c.f = f;
  uint x = c.i;
  return (ushort)((x + 0x7FFFu + ((x >> 16) & 1u)) >> 16);
}
__device__ __forceinline__ float gelu_erf(float x){
  return 0.5f * x * (1.0f + erff(x * 0.70710678118654752f));
}
__device__ __forceinline__ float gelu_tanh(float x){
  float y = 0.7978845608028654f * (x + 0.044715f * x * x * x);
  float e = __expf(2.f * y);
  float th = 1.f - 2.f / (e + 1.f);
  return 0.5f * x * (1.f + th);
}
__device__ __forceinline__ uint encf(float f){
  uint u = __float_as_uint(f);
  return (u & 0x80000000u) ? ~u : (u | 0x80000000u);
}
__device__ __forceinline__ float decf(uint u){
  return __uint_as_float((u & 0x80000000u) ? (u & 0x7FFFFFFFu) : ~u);
}
#define MFMA16(a,b,c) __builtin_amdgcn_mfma_f32_16x16x32_bf16((a),(b),(c),0,0,0)

// ---------------- init: flag (block 0) + cnt/last/Menc/S init (blocks 1..79) ----------------
__global__ void k_init(const uint* __restrict__ w, int* __restrict__ flag,
                       int* __restrict__ cnt, int* __restrict__ last,
                       uint* __restrict__ Menc, float* __restrict__ S){
  int t = threadIdx.x;
  if (blockIdx.x == 0){
    uint c = 0;
    for (int i = t; i < 4096; i += 256){
      uint v = w[i * 63];
      uint e = (v >> 7) & 0xFF;
      if (e >= 100 && e <= 140) c++;
    }
    __shared__ uint red[256];
    red[t] = c; __syncthreads();
    for (int s = 128; s > 0; s >>= 1){
      if (t < s) red[t] += red[t + s];
      __syncthreads();
    }
    if (t == 0) *flag = (red[0] < 2048) ? 1 : 0;
    return;
  }
  int idx = (blockIdx.x - 1) * 256 + t;
  if (idx < 10000) last[idx] = -1;
  else if (idx < 20000) cnt[idx - 10000] = 0;
  else if (idx < 20008) Menc[idx - 20000] = 0u;
  else if (idx < 20016) S[idx - 20008] = 0.f;
}

// ---------------- prep: count + cvt + zeros + weight transposes ----------------
__global__ void k_prep(
    const void* NF0, const int* __restrict__ dstI,
    const void* w1, const void* w2, const void* qw, const void* kvw,
    const void* ow1, const void* ow2,
    const void* b1, const void* b2, const void* qb, const void* kvb,
    const void* ob1, const void* ob2, const void* lg, const void* lb,
    int* __restrict__ cnt, int* __restrict__ last,
    ushort* NFc, float* Gagg, ushort* SB, ushort* KVW2,
    ushort* W1aT, ushort* W1bT, ushort* W1cT, ushort* W2T, ushort* QT, ushort* KVT,
    ushort* O1aT, ushort* O1bT, ushort* O2T, const int* flag)
{
  int f = *flag;
  int idx = blockIdx.x * 256 + threadIdx.x;
  if (idx < NE){
    int d = dstI[idx];
    atomicAdd(&cnt[d], 1);
    atomicMax(&last[d], idx);
    return;
  }
  idx -= NE;
  if (idx < 320000){
    if (f){
      float4 v = ((const float4*)NF0)[idx];
      ushort4 o; o.x=f2bf(v.x); o.y=f2bf(v.y); o.z=f2bf(v.z); o.w=f2bf(v.w);
      ((ushort4*)NFc)[idx] = o;
    } else ((ushort4*)NFc)[idx] = ((const ushort4*)NF0)[idx];
    return;
  }
  idx -= 320000;
  if (idx < 320000){ float4 z = {0.f,0.f,0.f,0.f}; ((float4*)Gagg)[idx] = z; return; }
  idx -= 320000;
  if (idx < 1024){
    const void* ps[8] = {b1,b2,qb,kvb,ob1,ob2,lg,lb};
    const void* p = ps[idx >> 7]; int j = idx & 127;
    SB[idx] = f ? f2bf(((const float*)p)[j]) : ((const ushort*)p)[j];
    return;
  }
  idx -= 1024;
  if (idx < 8192){
    KVW2[idx] = f ? f2bf(((const float*)kvw)[16384 + idx]) : ((const ushort*)kvw)[16384 + idx];
    return;
  }
  idx -= 8192;
  if (idx < 16384){ int c=idx>>7,k=idx&127; W1aT[idx] = f? f2bf(((const float*)w1)[k*128+c]) : ((const ushort*)w1)[k*128+c]; return; }
  idx -= 16384;
  if (idx < 16384){ int c=idx>>7,k=idx&127; W1bT[idx] = f? f2bf(((const float*)w1)[(128+k)*128+c]) : ((const ushort*)w1)[(128+k)*128+c]; return; }
  idx -= 16384;
  if (idx < 8192){ int c=idx>>6,k=idx&63;  W1cT[idx] = f? f2bf(((const float*)w1)[(256+k)*128+c]) : ((const ushort*)w1)[(256+k)*128+c]; return; }
  idx -= 8192;
  if (idx < 16384){ int c=idx>>7,k=idx&127; W2T[idx] = f? f2bf(((const float*)w2)[k*128+c]) : ((const ushort*)w2)[k*128+c]; return; }
  idx -= 16384;
  if (idx < 16384){ int c=idx>>7,k=idx&127; QT[idx]  = f? f2bf(((const float*)qw)[k*128+c]) : ((const ushort*)qw)[k*128+c]; return; }
  idx -= 16384;
  if (idx < 16384){ int c=idx>>7,k=idx&127; KVT[idx] = f? f2bf(((const float*)kvw)[k*128+c]) : ((const ushort*)kvw)[k*128+c]; return; }
  idx -= 16384;
  if (idx < 16384){ int c=idx>>7,k=idx&127; O1aT[idx] = f? f2bf(((const float*)ow1)[k*128+c]) : ((const ushort*)ow1)[k*128+c]; return; }
  idx -= 16384;
  if (idx < 16384){ int c=idx>>7,k=idx&127; O1bT[idx] = f? f2bf(((const float*)ow1)[(128+k)*128+c]) : ((const ushort*)ow1)[(128+k)*128+c]; return; }
  idx -= 16384;
  if (idx < 16384){ int c=idx>>7,k=idx&127; O2T[idx] = f? f2bf(((const float*)ow2)[k*128+c]) : ((const ushort*)ow2)[k*128+c]; return; }
}

// ---------------- scan ----------------
__global__ __launch_bounds__(1024) void k_scan(const int* __restrict__ cnt,
                                               int* __restrict__ fill){
  __shared__ int sc[1024];
  int t = threadIdx.x;
  int base = t * 10;
  int v[10]; int tot = 0;
  #pragma unroll
  for (int j = 0; j < 10; ++j){
    int idx = base + j;
    v[j] = (idx < NN) ? cnt[idx] : 0;
    tot += v[j];
  }
  sc[t] = tot; __syncthreads();
  for (int off = 1; off < 1024; off <<= 1){
    int x = (t >= off) ? sc[t - off] : 0;
    __syncthreads();
    sc[t] += x;
    __syncthreads();
  }
  int run = sc[t] - tot;
  #pragma unroll
  for (int j = 0; j < 10; ++j){
    int idx = base + j;
    if (idx < NN) fill[idx] = run;
    run += v[j];
  }
}

// ---------------- fill (blocks 0..1249, int4-packed scatter) + nodepack (1250..1874) ----------------
__global__ __launch_bounds__(256) void k_fillperm(
    const int* __restrict__ srcI, const int* __restrict__ dstI,
    int* __restrict__ fill, int4* __restrict__ sde,
    const ushort* __restrict__ NFc,
    const ushort* __restrict__ W1aT, const ushort* __restrict__ W1bT,
    const ushort* __restrict__ QT,  const ushort* __restrict__ KVT,
    const ushort* __restrict__ SB,
    ushort* __restrict__ PA, ushort* __restrict__ PB,
    ushort* __restrict__ Qb, ushort* __restrict__ KV1)
{
  int t = threadIdx.x;
  if (blockIdx.x >= 1250){
    // ---- nodepack: PA, PB(+b1), Qb(+qb), KV1(+kvb) ----
    int l = t & 63, w = t >> 6;
    int m = l & 15, g = l >> 4;
    int row0 = ((int)blockIdx.x - 1250) * 16;
    const ushort* WT = (w==0) ? W1aT : (w==1) ? W1bT : (w==2) ? QT : KVT;
    ushort*       OUT= (w==0) ? PA   : (w==1) ? PB   : (w==2) ? Qb : KV1;
    const f32x4 FZ = {0.f,0.f,0.f,0.f};
    f32x4 acc[8];
    #pragma unroll
    for (int i = 0; i < 8; ++i) acc[i] = FZ;
    int arow = row0 + m;
    #pragma unroll
    for (int ks = 0; ks < 4; ++ks){
      int koff = ks * 32 + g * 8;
      bf16x8 a = *reinterpret_cast<const bf16x8*>(NFc + (size_t)arow * 128 + koff);
      #pragma unroll
      for (int nt = 0; nt < 8; ++nt){
        bf16x8 b = *reinterpret_cast<const bf16x8*>(WT + (size_t)(nt*16+m) * 128 + koff);
        acc[nt] = MFMA16(a, b, acc[nt]);
      }
    }
    #pragma unroll
    for (int nt = 0; nt < 8; ++nt){
      int col = nt * 16 + m;
      float bb = (w==1) ? bf2f(SB[col]) : (w==2) ? bf2f(SB[256+col]) : (w==3) ? bf2f(SB[384+col]) : 0.f;
      #pragma unroll
      for (int r = 0; r < 4; ++r){
        int row = row0 + g * 4 + r;
        OUT[(size_t)row * 128 + col] = f2bf(acc[nt][r] + bb);
      }
    }
    return;
  }
  // ---- fill: single int4 scatter per edge {src, dst, e, 0} ----
  int e = blockIdx.x * 256 + t;
  int d = dstI[e];
  int s = srcI[e];
  int p = atomicAdd(&fill[d], 1);
  int4 v; v.x = s; v.y = d; v.z = e; v.w = 0;
  sde[p] = v;
}

// ---------------- edge (blocks 0..4999, 64 edges, gathered EA) + attn (5000..5624) ----------------
__global__ __launch_bounds__(256) void k_edgeattn(
    const ushort* __restrict__ PA, const ushort* __restrict__ PB,
    const int4* __restrict__ sde,
    const ushort* __restrict__ W1cT,
    float* __restrict__ Gagg,
    const ushort* __restrict__ Qb, const ushort* __restrict__ KV1,
    const ushort* __restrict__ EAb, const float* __restrict__ EAf,
    const ushort* __restrict__ KVW2,
    const int* __restrict__ srcI, const int* __restrict__ last,
    float* __restrict__ attn, uint* __restrict__ Menc, const int* __restrict__ flag)
{
  __shared__ __align__(16) char Hs[64 * 256];    // 16KB; attn branch overlays ea_s here
  __shared__ __align__(16) char EAl[64 * 128];   // 8KB gathered EA tile (bf16, swizzled)
  __shared__ int sIdx[64], dIdx[64], eIdx[64];
  __shared__ int eN[16], sN[16];
  __shared__ uint lmax[8];
  int t = threadIdx.x;

  if (blockIdx.x >= 5000){
    // ---------- attention logits ----------
    float (*ea_s)[64] = reinterpret_cast<float(*)[64]>(Hs);
    int n0 = ((int)blockIdx.x - 5000) * 16;
    if (t < 16){
      int e = last[n0 + t];
      eN[t] = e;
      sN[t] = (e >= 0) ? srcI[e] : 0;
    }
    if (t < 8) lmax[t] = 0u;
    __syncthreads();
    int F = *flag;
    for (int i = t; i < 1024; i += 256){
      int nn = i >> 6, k = i & 63;
      int e = eN[nn];
      int ee = (e >= 0) ? e : 0;
      float v = F ? EAf[(size_t)ee * 64 + k] : bf2f(EAb[(size_t)ee * 64 + k]);
      ea_s[nn][k] = (e >= 0) ? v : 0.0f;
    }
    __syncthreads();
    int j = t & 127;
    int half = t >> 7;
    float acc[8];
    #pragma unroll
    for (int i = 0; i < 8; ++i) acc[i] = 0.f;
    for (int k = 0; k < 64; ++k){
      float wv = bf2f(KVW2[(size_t)k * 128 + j]);
      #pragma unroll
      for (int nn = 0; nn < 8; ++nn) acc[nn] += ea_s[half * 8 + nn][k] * wv;
    }
    #pragma unroll
    for (int nn = 0; nn < 8; ++nn){
      int nl = half * 8 + nn;
      int n = n0 + nl;
      int e = eN[nl];
      float kvv = acc[nn] + bf2f(KV1[(size_t)sN[nl] * 128 + j]);
      float qv  = bf2f(Qb[(size_t)n * 128 + j]);
      float p = qv * kvv;
      p += __shfl_xor(p, 1); p += __shfl_xor(p, 2);
      p += __shfl_xor(p, 4); p += __shfl_xor(p, 8);
      if ((j & 15) == 0 && e >= 0){
        float v = p * 0.25f;
        attn[(size_t)n * 8 + (j >> 4)] = v;
        atomicMax(&lmax[j >> 4], encf(v));
      }
    }
    __syncthreads();
    if (t < 8 && lmax[t]) atomicMax(&Menc[t], lmax[t]);
    return;
  }

  // ---------- edge MLP + segmented reduce (64-edge tile) ----------
  int p0 = blockIdx.x * 64;
  int l = t & 63, w = t >> 6;
  int m = l & 15, g = l >> 4;

  if (t < 64){
    int4 v = sde[p0 + t];
    sIdx[t] = v.x; dIdx[t] = v.y; eIdx[t] = v.z;
  }
  __syncthreads();
  int F = *flag;

  // stage gathered EA row -> EAl (bf16, swizzled) and PS = PA[src]+PB[dst] -> Hs
  {
    int r = t >> 2, q = t & 3;          // 4 threads per row
    int e = eIdx[r];
    int kb = q * 32;                     // byte offset within 128B bf16 row
    if (F){
      const float* src = EAf + (size_t)e * 64 + q * 16;
      float4 v0 = *reinterpret_cast<const float4*>(src);
      float4 v1 = *reinterpret_cast<const float4*>(src + 4);
      float4 v2 = *reinterpret_cast<const float4*>(src + 8);
      float4 v3 = *reinterpret_cast<const float4*>(src + 12);
      bf16x8 o0, o1;
      o0[0]=(__bf16)v0.x; o0[1]=(__bf16)v0.y; o0[2]=(__bf16)v0.z; o0[3]=(__bf16)v0.w;
      o0[4]=(__bf16)v1.x; o0[5]=(__bf16)v1.y; o0[6]=(__bf16)v1.z; o0[7]=(__bf16)v1.w;
      o1[0]=(__bf16)v2.x; o1[1]=(__bf16)v2.y; o1[2]=(__bf16)v2.z; o1[3]=(__bf16)v2.w;
      o1[4]=(__bf16)v3.x; o1[5]=(__bf16)v3.y; o1[6]=(__bf16)v3.z; o1[7]=(__bf16)v3.w;
      *reinterpret_cast<bf16x8*>(&EAl[(r * 128 + kb)      ^ ((r & 7) << 4)]) = o0;
      *reinterpret_cast<bf16x8*>(&EAl[(r * 128 + kb + 16) ^ ((r & 7) << 4)]) = o1;
    } else {
      const ushort* src = EAb + (size_t)e * 64 + q * 16;
      *reinterpret_cast<bf16x8*>(&EAl[(r * 128 + kb)      ^ ((r & 7) << 4)]) =
        *reinterpret_cast<const bf16x8*>(src);
      *reinterpret_cast<bf16x8*>(&EAl[(r * 128 + kb + 16) ^ ((r & 7) << 4)]) =
        *reinterpret_cast<const bf16x8*>(src + 8);
    }
    int sr = sIdx[r], dr = dIdx[r];
    #pragma unroll
    for (int j = 0; j < 4; ++j){
      int c8 = q * 4 + j;
      bf16x8 pa = *reinterpret_cast<const bf16x8*>(PA + (size_t)sr * 128 + c8 * 8);
      bf16x8 pb = *reinterpret_cast<const bf16x8*>(PB + (size_t)dr * 128 + c8 * 8);
      bf16x8 ps;
      #pragma unroll
      for (int k = 0; k < 8; ++k) ps[k] = (__bf16)((float)pa[k] + (float)pb[k]);
      int byte = (r * 256 + c8 * 16) ^ ((r & 7) << 4);
      *reinterpret_cast<bf16x8*>(&Hs[byte]) = ps;
    }
  }
  __syncthreads();

  // EA GEMM: each wave owns 16 rows x 128 cols, K=64; A from LDS (2-way conflict = free)
  const f32x4 FZ = {0.f,0.f,0.f,0.f};
  f32x4 acc[8];
  #pragma unroll
  for (int i = 0; i < 8; ++i) acc[i] = FZ;

  #pragma unroll
  for (int ks = 0; ks < 2; ++ks){
    int row = w * 16 + m;
    bf16x8 af = *reinterpret_cast<const bf16x8*>(&EAl[(row * 128 + ks * 64 + g * 16) ^ ((row & 7) << 4)]);
    #pragma unroll
    for (int nt = 0; nt < 8; ++nt){
      bf16x8 b = *reinterpret_cast<const bf16x8*>(W1cT + (size_t)(nt * 16 + m) * 64 + ks * 32 + g * 8);
      acc[nt] = MFMA16(af, b, acc[nt]);
    }
  }

  // G = gelu(acc + PS); write back to same LDS slot (same-thread RMW, safe)
  #pragma unroll
  for (int nt = 0; nt < 8; ++nt){
    int col = nt * 16 + m;
    #pragma unroll
    for (int r = 0; r < 4; ++r){
      int row = w * 16 + g * 4 + r;
      int byte = (row * 256 + col * 2) ^ ((row & 7) << 4);
      float x = acc[nt][r] + bf2f(*reinterpret_cast<const ushort*>(&Hs[byte]));
      *reinterpret_cast<ushort*>(&Hs[byte]) = f2bf(gelu_tanh(x));
    }
  }
  __syncthreads();

  // column-per-thread segmented reduce: wave-uniform flush, contiguous lanes per atomic
  {
    int c = t & 127, hh = t >> 7;
    int rS = hh * 32, rE = rS + 32;
    float run = 0.f;
    int cur = dIdx[rS];
    for (int r = rS; r < rE; ++r){
      int d = dIdx[r];
      if (d != cur){
        unsafeAtomicAdd(&Gagg[(size_t)cur * 128 + c], run);
        run = 0.f; cur = d;
      }
      int byte = (r * 256 + c * 2) ^ ((r & 7) << 4);
      run += bf2f(*reinterpret_cast<const ushort*>(&Hs[byte]));
    }
    unsafeAtomicAdd(&Gagg[(size_t)cur * 128 + c], run);
  }
}

// ---------------- softmax denominators ----------------
__global__ __launch_bounds__(256) void k_asum(
    const float* __restrict__ attn, const int* __restrict__ last,
    const uint* __restrict__ Menc, float* __restrict__ S)
{
  __shared__ float red[256][8];
  int t = threadIdx.x;
  float M[8];
  #pragma unroll
  for (int h = 0; h < 8; ++h) M[h] = decf(Menc[h]);
  float p[8];
  #pragma unroll
  for (int h = 0; h < 8; ++h) p[h] = 0.f;
  for (int n = blockIdx.x * 256 + t; n < NN; n += gridDim.x * 256){
    if (last[n] >= 0){
      #pragma unroll
      for (int h = 0; h < 8; ++h) p[h] += __expf(attn[(size_t)n * 8 + h] - M[h]);
    }
  }
  #pragma unroll
  for (int h = 0; h < 8; ++h) red[t][h] = p[h];
  __syncthreads();
  for (int s = 128; s > 0; s >>= 1){
    if (t < s){
      #pragma unroll
      for (int h = 0; h < 8; ++h) red[t][h] += red[t + s][h];
    }
    __syncthreads();
  }
  if (t < 8) atomicAdd(&S[t], red[0][t]);
}

// ---------------- fused node tail: Gagg@W2 -> z -> z@O1b + NF@O1a -> gelu -> T1(LDS)
//                  -> T1@O2 -> +ob2 + residual -> LayerNorm -> out ----------------
__global__ __launch_bounds__(256) void k_aggln(
    const float* __restrict__ Gagg, const ushort* __restrict__ W2T,
    const ushort* __restrict__ O1aT, const ushort* __restrict__ O1bT,
    const ushort* __restrict__ O2T,
    const ushort* __restrict__ SB,   // b2=SB+128, ob1=SB+512, ob2=SB+640, ln_g=SB+768, ln_b=SB+896
    const int* __restrict__ cnt, const int* __restrict__ last,
    const float* __restrict__ attn, const uint* __restrict__ Menc,
    const float* __restrict__ S,
    const ushort* __restrict__ NFc, void* __restrict__ out,
    const int* __restrict__ flag)
{
  __shared__ __align__(16) char Zs[64 * 256];
  int t = threadIdx.x, l = t & 63, w = t >> 6;
  int m = l & 15, g = l >> 4;
  int row0 = blockIdx.x * 64 + w * 16;
  int F = *flag;

  float M[8], Sinv[8];
  #pragma unroll
  for (int h = 0; h < 8; ++h){ M[h] = decf(Menc[h]); Sinv[h] = 1.0f / S[h]; }

  int arow = row0 + m; if (arow >= NN) arow = NN - 1;
  const f32x4 FZ = {0.f,0.f,0.f,0.f};

  // ---- stage 1: y = Gagg@W2 (hi/lo split) ----
  f32x4 acc[8];
  #pragma unroll
  for (int i = 0; i < 8; ++i) acc[i] = FZ;
  #pragma unroll
  for (int ks = 0; ks < 4; ++ks){
    const float* gp = Gagg + (size_t)arow * 128 + ks * 32 + g * 8;
    float4 u0 = *reinterpret_cast<const float4*>(gp);
    float4 u1 = *reinterpret_cast<const float4*>(gp + 4);
    float gv[8] = {u0.x,u0.y,u0.z,u0.w,u1.x,u1.y,u1.z,u1.w};
    bf16x8 hi, lo;
    #pragma unroll
    for (int k = 0; k < 8; ++k){
      hi[k] = (__bf16)gv[k];
      lo[k] = (__bf16)(gv[k] - (float)hi[k]);
    }
    #pragma unroll
    for (int nt = 0; nt < 8; ++nt){
      bf16x8 b = *reinterpret_cast<const bf16x8*>(W2T + (size_t)(nt*16+m) * 128 + ks * 32 + g * 8);
      acc[nt] = MFMA16(hi, b, acc[nt]);
      acc[nt] = MFMA16(lo, b, acc[nt]);
    }
  }

  // z = (y + cn*b2) * aw -> Zs (swizzled)
  #pragma unroll
  for (int r = 0; r < 4; ++r){
    int row = row0 + g * 4 + r;
    int rr = (row < NN) ? row : NN - 1;
    float cn = (float)cnt[rr];
    int lst = last[rr];
    int Lr = w * 16 + g * 4 + r;
    #pragma unroll
    for (int nt = 0; nt < 8; ++nt){
      int col = nt * 16 + m;
      float aw = (lst >= 0) ? __expf(attn[(size_t)rr * 8 + nt] - M[nt]) * Sinv[nt] : 0.f;
      float z = (acc[nt][r] + cn * bf2f(SB[128 + col])) * aw;
      int byte = (Lr * 256 + col * 2) ^ ((Lr & 7) << 4);
      *reinterpret_cast<ushort*>(&Zs[byte]) = f2bf(z);
    }
  }
  __syncthreads();

  // ---- stage 2: T1 = gelu(z@O1b + NF@O1a + ob1) ----
  f32x4 acc2[8];
  #pragma unroll
  for (int i = 0; i < 8; ++i) acc2[i] = FZ;
  int La = w * 16 + m;
  #pragma unroll
  for (int ks = 0; ks < 4; ++ks){
    int koff = ks * 32 + g * 8;
    bf16x8 az = *reinterpret_cast<const bf16x8*>(&Zs[(La * 256 + koff * 2) ^ ((La & 7) << 4)]);
    bf16x8 an = *reinterpret_cast<const bf16x8*>(NFc + (size_t)arow * 128 + koff);
    #pragma unroll
    for (int nt = 0; nt < 8; ++nt){
      bf16x8 b1v = *reinterpret_cast<const bf16x8*>(O1bT + (size_t)(nt*16+m) * 128 + koff);
      bf16x8 b2v = *reinterpret_cast<const bf16x8*>(O1aT + (size_t)(nt*16+m) * 128 + koff);
      acc2[nt] = MFMA16(az, b1v, acc2[nt]);
      acc2[nt] = MFMA16(an, b2v, acc2[nt]);
    }
  }
  __syncthreads();   // all z reads complete before overwrite

  // write T1 into Zs (overwrite z)
  #pragma unroll
  for (int nt = 0; nt < 8; ++nt){
    int col = nt * 16 + m;
    float bb = bf2f(SB[512 + col]);
    #pragma unroll
    for (int r = 0; r < 4; ++r){
      int Lr = w * 16 + g * 4 + r;
      float v = gelu_erf(acc2[nt][r] + bb);
      int byte = (Lr * 256 + col * 2) ^ ((Lr & 7) << 4);
      *reinterpret_cast<ushort*>(&Zs[byte]) = f2bf(v);
    }
  }
  __syncthreads();

  // ---- stage 3: out = LN(T1@O2 + ob2 + NF) ----
  f32x4 acc3[8];
  #pragma unroll
  for (int i = 0; i < 8; ++i) acc3[i] = FZ;
  #pragma unroll
  for (int ks = 0; ks < 4; ++ks){
    int koff = ks * 32 + g * 8;
    bf16x8 a = *reinterpret_cast<const bf16x8*>(&Zs[(La * 256 + koff * 2) ^ ((La & 7) << 4)]);
    #pragma unroll
    for (int nt = 0; nt < 8; ++nt){
      bf16x8 b = *reinterpret_cast<const bf16x8*>(O2T + (size_t)(nt*16+m) * 128 + koff);
      acc3[nt] = MFMA16(a, b, acc3[nt]);
    }
  }
  #pragma unroll
  for (int r = 0; r < 4; ++r){
    int row = row0 + g * 4 + r;
    bool ok = row < NN;
    int rr = ok ? row : NN - 1;
    float x[8]; float s = 0.f, q = 0.f;
    #pragma unroll
    for (int nt = 0; nt < 8; ++nt){
      int col = nt * 16 + m;
      float xv = acc3[nt][r] + bf2f(SB[640 + col]) + bf2f(NFc[(size_t)rr * 128 + col]);
      x[nt] = xv; s += xv; q += xv * xv;
    }
    #pragma unroll
    for (int msk = 1; msk < 16; msk <<= 1){
      s += __shfl_xor(s, msk);
      q += __shfl_xor(q, msk);
    }
    float mean = s * (1.0f / 128.0f);
    float var  = q * (1.0f / 128.0f) - mean * mean;
    float rs = rsqrtf(var + 1e-5f);
    if (ok){
      #pragma unroll
      for (int nt = 0; nt < 8; ++nt){
        int col = nt * 16 + m;
        float y = (x[nt] - mean) * rs * bf2f(SB[768 + col]) + bf2f(SB[896 + col]);
        if (F) ((float*)out)[(size_t)row * 128 + col] = y;
        else   ((ushort*)out)[(size_t)row * 128 + col] = f2bf(y);
      }
    }
  }
}

// ---------------- host ----------------
extern "C" void kernel_launch(void* const* d_in, const int* in_sizes, int n_in,
                              void* d_out, int out_size, void* d_ws, size_t ws_size,
                              hipStream_t stream)
{
  const void* NF0  = d_in[0];
  const void* EA0  = d_in[1];
  const void* w1   = d_in[2];
  const void* b1   = d_in[3];
  const void* w2   = d_in[4];
  const void* b2   = d_in[5];
  const void* qw   = d_in[6];
  const void* qb   = d_in[7];
  const void* kvw  = d_in[8];
  const void* kvb  = d_in[9];
  const void* ow1  = d_in[10];
  const void* ob1  = d_in[11];
  const void* ow2  = d_in[12];
  const void* ob2  = d_in[13];
  const void* lg   = d_in[14];
  const void* lb   = d_in[15];
  const int*  srcI = (const int*)d_in[16];
  const int*  dstI = srcI + NE;

  char* ws = (char*)d_ws;
  size_t off = 0;
  auto alloc = [&](size_t bytes) -> void* {
    void* p = ws + off;
    off = (off + bytes + 255) & ~(size_t)255;
    return p;
  };
  int*    flag  = (int*)   alloc(4);
  ushort* NFc   = (ushort*)alloc((size_t)NN * 128 * 2);
  ushort* SB    = (ushort*)alloc(8 * 128 * 2);
  ushort* KVW2  = (ushort*)alloc(64 * 128 * 2);
  ushort* W1aT  = (ushort*)alloc(128 * 128 * 2);
  ushort* W1bT  = (ushort*)alloc(128 * 128 * 2);
  ushort* W1cT  = (ushort*)alloc(128 * 64 * 2);
  ushort* W2T   = (ushort*)alloc(128 * 128 * 2);
  ushort* QT    = (ushort*)alloc(128 * 128 * 2);
  ushort* KVT   = (ushort*)alloc(128 * 128 * 2);
  ushort* O1aT  = (ushort*)alloc(128 * 128 * 2);
  ushort* O1bT  = (ushort*)alloc(128 * 128 * 2);
  ushort* O2T   = (ushort*)alloc(128 * 128 * 2);
  int*    last  = (int*)   alloc(NN * 4);
  int*    cnt   = (int*)   alloc(NN * 4);
  int*    fill  = (int*)   alloc(NN * 4);
  int4*   sde   = (int4*)  alloc((size_t)NE * 16);
  float*  attn  = (float*) alloc(NN * 8 * 4);
  uint*   Menc  = (uint*)  alloc(8 * 4);
  float*  S     = (float*) alloc(8 * 4);
  ushort* PA    = (ushort*)alloc((size_t)NN * 128 * 2);
  ushort* PB    = (ushort*)alloc((size_t)NN * 128 * 2);
  ushort* Qb    = (ushort*)alloc((size_t)NN * 128 * 2);
  ushort* KV1   = (ushort*)alloc((size_t)NN * 128 * 2);
  float*  Gagg  = (float*) alloc((size_t)NN * 128 * 4);

  k_init<<<80, 256, 0, stream>>>((const uint*)NF0, flag, cnt, last, Menc, S);
  k_prep<<<4330, 256, 0, stream>>>(NF0, dstI, w1, w2, qw, kvw, ow1, ow2,
                                   b1, b2, qb, kvb, ob1, ob2, lg, lb,
                                   cnt, last, NFc, Gagg, SB, KVW2,
                                   W1aT, W1bT, W1cT, W2T, QT, KVT, O1aT, O1bT, O2T, flag);
  k_scan<<<1, 1024, 0, stream>>>(cnt, fill);
  k_fillperm<<<1875, 256, 0, stream>>>(srcI, dstI, fill, sde,
                                       NFc, W1aT, W1bT, QT, KVT, SB,
                                       PA, PB, Qb, KV1);
  k_edgeattn<<<5625, 256, 0, stream>>>(PA, PB, sde, W1cT, Gagg,
                                       Qb, KV1, (const ushort*)EA0, (const float*)EA0,
                                       KVW2, srcI, last, attn, Menc, flag);
  k_asum<<<40, 256, 0, stream>>>(attn, last, Menc, S);
  k_aggln<<<157, 256, 0, stream>>>(Gagg, W2T, O1aT, O1bT, O2T, SB, cnt, last,
                                   attn, Menc, S, NFc, d_out, flag);
}